// Round 5
// baseline (3458.168 us; speedup 1.0000x reference)
//
#include <hip/hip_runtime.h>

#define B_   64
#define C_   256
#define D_   128
#define HW_  1024
#define K_   1024
#define N_   65536
#define MARGIN 1e-5f

// numpy pairwise-sum emulation for n=128 contiguous f32 — SCALAR 8-accumulator
// path: r[j]=a[j]; for i=8..120 step 8: r[j]+=a[i+j];
// res = ((r0+r1)+(r2+r3)) + ((r4+r5)+(r6+r7)).   (verified: R4 passed)
template <typename F>
__device__ __forceinline__ float np_sum128(F ld) {
#pragma clang fp contract(off)
    float r0 = ld(0), r1 = ld(1), r2 = ld(2), r3 = ld(3);
    float r4 = ld(4), r5 = ld(5), r6 = ld(6), r7 = ld(7);
#pragma unroll
    for (int i = 8; i < 128; i += 8) {
        r0 = r0 + ld(i + 0); r1 = r1 + ld(i + 1);
        r2 = r2 + ld(i + 2); r3 = r3 + ld(i + 3);
        r4 = r4 + ld(i + 4); r5 = r5 + ld(i + 5);
        r6 = r6 + ld(i + 6); r7 = r7 + ld(i + 7);
    }
    return ((r0 + r1) + (r2 + r3)) + ((r4 + r5) + (r6 + r7));
}

// ---------------- K0: enorm[k] = np.sum(embed[k]*embed[k]) emulated ----------------
__global__ __launch_bounds__(256) void k0_norms(const float* __restrict__ embed,
                                                float* __restrict__ enorm) {
#pragma clang fp contract(off)
    int k = blockIdx.x * 256 + threadIdx.x;
    if (k >= K_) return;
    const float* e = embed + (size_t)k * D_;
    enorm[k] = np_sum128([&](int i) { float v = e[i]; return v * v; });
}

// ---------------- K1: zf[n][d] = einsum-f32 emulation (sequential c, mul+add, no FMA) ----------------
__global__ __launch_bounds__(256) void k1_proj(const float* __restrict__ z,
                                               const float* __restrict__ w,
                                               const float* __restrict__ bias,
                                               float* __restrict__ zp) {
#pragma clang fp contract(off)
    __shared__ float zs[64][64];    // [cc][hw_l]
    __shared__ float wsh[64][128];  // [cc][d]
    const int b   = blockIdx.x >> 4;
    const int hw0 = (blockIdx.x & 15) << 6;
    const int t   = threadIdx.x;
    const int hwg = (t & 7) * 8;
    const int dg  = (t >> 3) * 4;

    float acc[8][4];
#pragma unroll
    for (int i = 0; i < 8; ++i)
#pragma unroll
        for (int j = 0; j < 4; ++j) acc[i][j] = 0.f;

    for (int ct = 0; ct < C_; ct += 64) {
        __syncthreads();
#pragma unroll
        for (int i = 0; i < 16; ++i) {
            int idx = i * 256 + t;
            int cc = idx >> 6, hwl = idx & 63;
            zs[cc][hwl] = z[(((size_t)b * C_ + ct + cc) << 10) + hw0 + hwl];
        }
#pragma unroll
        for (int i = 0; i < 32; ++i) {
            int idx = i * 256 + t;
            int cc = idx >> 7, d = idx & 127;
            wsh[cc][d] = w[(size_t)d * C_ + ct + cc];
        }
        __syncthreads();
#pragma unroll 2
        for (int cc = 0; cc < 64; ++cc) {       // c strictly ascending across ct blocks
            float4 za = *(const float4*)&zs[cc][hwg];
            float4 zb = *(const float4*)&zs[cc][hwg + 4];
            float4 wv = *(const float4*)&wsh[cc][dg];
            float zv[8]  = {za.x, za.y, za.z, za.w, zb.x, zb.y, zb.z, zb.w};
            float wva[4] = {wv.x, wv.y, wv.z, wv.w};
#pragma unroll
            for (int i = 0; i < 8; ++i)
#pragma unroll
                for (int j = 0; j < 4; ++j) {
                    float p = zv[i] * wva[j];    // round mul
                    acc[i][j] = acc[i][j] + p;   // round add (no contraction)
                }
        }
    }
#pragma unroll
    for (int i = 0; i < 8; ++i)
#pragma unroll
        for (int j = 0; j < 4; ++j) {
            float v = acc[i][j] + bias[dg + j];
            zp[(((size_t)b * HW_ + hw0 + hwg + i) << 7) + dg + j] = v;
        }
}

// ---------------- K2: argmin_k of np-f32 B = fl32(fl32(Z - 2*zdot) + E) ----------------
// z-row in VGPRs (launch_bounds 256,2 -> 256-reg budget, no LDS demotion).
// zl LDS copy used ONLY by the rare exact-refine path.
__global__ __launch_bounds__(256, 2) void k2_argmin(const float* __restrict__ zp,
                                                    const float* __restrict__ embed,
                                                    const float* __restrict__ enorm,
                                                    int* __restrict__ bestk_ws,
                                                    float* __restrict__ out_idx) {
#pragma clang fp contract(off)
    __shared__ float zl[64 * 128];
    __shared__ float red_B[256];
    __shared__ int   red_k[256];
    const int t  = threadIdx.x;
    const int n0 = blockIdx.x * 64;
    const int rl = t & 63;

#pragma unroll
    for (int i = 0; i < 32; ++i) {               // stage rows for refine path (coalesced)
        int idx = i * 256 + t;
        zl[idx] = zp[(size_t)n0 * 128 + idx];
    }

    // own row -> registers, straight from global (L2-resident; defeats LDS remat)
    float zr[128];
    {
        const float4* zrow_g = (const float4*)(zp + ((size_t)(n0 + rl) << 7));
#pragma unroll
        for (int j = 0; j < 32; ++j) {
            float4 v = zrow_g[j];
            zr[j * 4 + 0] = v.x; zr[j * 4 + 1] = v.y;
            zr[j * 4 + 2] = v.z; zr[j * 4 + 3] = v.w;
        }
    }
    __syncthreads();

    // znorm from registers: np.sum(zf*zf) — squares rounded, scalar-8 pairwise tree
    const float znorm = np_sum128([&](int i) { float v = zr[i]; return v * v; });

    const float* zrow = &zl[rl * 128];           // refine-only
    const int kq   = __builtin_amdgcn_readfirstlane(t >> 6);
    const int kbeg = kq * 256;

    float best32 = 1e30f;          // f32 prefilter proxy: enorm - 2 z.e
    float bestB  = 1e30f;          // np-emulated quantized dist
    int   bestk  = K_;
    unsigned long long cand64 = 0; // 6 x 10-bit packed candidates (no scratch array)
    int   cnt = 0;

    auto refine = [&](int kk) {
#pragma clang fp contract(off)
        const float* e = embed + ((size_t)kk << 7);
        float s = 0.f;                        // sgemm: ascending-k f32 FMA chain
#pragma unroll 1
        for (int d2 = 0; d2 < 128; ++d2)
            s = fmaf(zrow[d2], e[d2], s);
        float T  = 2.0f * s;
        float A  = znorm - T;                 // bin-maker 1 (mag ~13)
        float Bv = A + enorm[kk];             // bin-maker 2
        if (Bv < bestB || (Bv == bestB && kk < bestk)) { bestB = Bv; bestk = kk; }
    };
    auto flush = [&]() {
#pragma unroll
        for (int i = 0; i < 6; ++i)
            if (i < cnt) refine((int)((cand64 >> (10 * i)) & 1023ull));
        cand64 = 0; cnt = 0;
    };

#pragma unroll 1
    for (int k = kbeg; k < kbeg + 256; ++k) {
        const float4* e4 = (const float4*)(embed) + ((size_t)k << 5);
        float s0 = 0.f, s1 = 0.f, s2 = 0.f, s3 = 0.f;
#pragma unroll
        for (int j = 0; j < 32; j += 4) {
            float4 a  = e4[j + 0];
            float4 b2 = e4[j + 1];
            float4 c2 = e4[j + 2];
            float4 d2 = e4[j + 3];
            s0 = fmaf(zr[4*j +  0], a.x,  s0); s0 = fmaf(zr[4*j +  1], a.y,  s0);
            s0 = fmaf(zr[4*j +  2], a.z,  s0); s0 = fmaf(zr[4*j +  3], a.w,  s0);
            s1 = fmaf(zr[4*j +  4], b2.x, s1); s1 = fmaf(zr[4*j +  5], b2.y, s1);
            s1 = fmaf(zr[4*j +  6], b2.z, s1); s1 = fmaf(zr[4*j +  7], b2.w, s1);
            s2 = fmaf(zr[4*j +  8], c2.x, s2); s2 = fmaf(zr[4*j +  9], c2.y, s2);
            s2 = fmaf(zr[4*j + 10], c2.z, s2); s2 = fmaf(zr[4*j + 11], c2.w, s2);
            s3 = fmaf(zr[4*j + 12], d2.x, s3); s3 = fmaf(zr[4*j + 13], d2.y, s3);
            s3 = fmaf(zr[4*j + 14], d2.z, s3); s3 = fmaf(zr[4*j + 15], d2.w, s3);
        }
        float s    = (s0 + s1) + (s2 + s3);
        float dist = fmaf(-2.f, s, enorm[k]);
        if (dist < best32 + MARGIN) {        // np-winner provably buffered (window 5.8e-6)
            best32 = fminf(best32, dist);
            if (cnt == 6) flush();
            cand64 |= (unsigned long long)(k & 1023) << (10 * cnt);
            ++cnt;
        }
    }
    flush();

    red_B[t] = bestB; red_k[t] = bestk;
    __syncthreads();
    if (t < 64) {
        float bB = red_B[t]; int bk = red_k[t];
#pragma unroll
        for (int q = 1; q < 4; ++q) {
            float Bq = red_B[q * 64 + t]; int kq2 = red_k[q * 64 + t];
            if (Bq < bB || (Bq == bB && kq2 < bk)) { bB = Bq; bk = kq2; }
        }
        bestk_ws[n0 + t] = bk;
        out_idx[n0 + t]  = (float)bk;
    }
}

// ---------------- K3: gather + NCHW transpose ----------------
__global__ __launch_bounds__(256) void k3_gather(const float* __restrict__ embed,
                                                 const int* __restrict__ bestk,
                                                 float* __restrict__ out0) {
    __shared__ float tile[64][129];
    const int b   = blockIdx.x >> 4;
    const int hw0 = (blockIdx.x & 15) << 6;
    const int t   = threadIdx.x;
    const int n0  = b * HW_ + hw0;
#pragma unroll
    for (int i = 0; i < 32; ++i) {
        int idx = i * 256 + t;
        int hwl = idx >> 7, d = idx & 127;
        int k = bestk[n0 + hwl];
        tile[hwl][d] = embed[(size_t)k * 128 + d];
    }
    __syncthreads();
#pragma unroll
    for (int i = 0; i < 32; ++i) {
        int idx = i * 256 + t;
        int d = idx >> 6, hwl = idx & 63;
        out0[(((size_t)b * D_ + d) << 10) + hw0 + hwl] = tile[hwl][d];
    }
}

extern "C" void kernel_launch(void* const* d_in, const int* in_sizes, int n_in,
                              void* d_out, int out_size, void* d_ws, size_t ws_size,
                              hipStream_t stream) {
    const float* z     = (const float*)d_in[0];
    const float* pw    = (const float*)d_in[1];
    const float* pb    = (const float*)d_in[2];
    const float* embed = (const float*)d_in[3];

    float* out0 = (float*)d_out;
    float* out1 = (float*)d_out + (size_t)B_ * D_ * HW_;

    const size_t zp_bytes = (size_t)N_ * D_ * 4;           // 32 MB
    float* zp    = (float*)d_ws;
    float* enorm = (float*)((char*)d_ws + zp_bytes);
    int*   bestk = (int*)  ((char*)d_ws + zp_bytes + 4096);

    hipLaunchKernelGGL(k0_norms,  dim3(4),    dim3(256), 0, stream, embed, enorm);
    hipLaunchKernelGGL(k1_proj,   dim3(1024), dim3(256), 0, stream, z, pw, pb, zp);
    hipLaunchKernelGGL(k2_argmin, dim3(1024), dim3(256), 0, stream, zp, embed, enorm, bestk, out1);
    hipLaunchKernelGGL(k3_gather, dim3(1024), dim3(256), 0, stream, embed, bestk, out0);
}

// Round 6
// 1762.144 us; speedup vs baseline: 1.9625x; 1.9625x over previous
//
#include <hip/hip_runtime.h>

#define B_   64
#define C_   256
#define D_   128
#define HW_  1024
#define K_   1024
#define N_   65536
#define MARGIN 1e-5f

// numpy pairwise-sum emulation for n=128 contiguous f32 — SCALAR 8-accumulator
// path: r[j]=a[j]; for i=8..120 step 8: r[j]+=a[i+j];
// res = ((r0+r1)+(r2+r3)) + ((r4+r5)+(r6+r7)).   (verified: R4/R5 passed)
template <typename F>
__device__ __forceinline__ float np_sum128(F ld) {
#pragma clang fp contract(off)
    float r0 = ld(0), r1 = ld(1), r2 = ld(2), r3 = ld(3);
    float r4 = ld(4), r5 = ld(5), r6 = ld(6), r7 = ld(7);
#pragma unroll
    for (int i = 8; i < 128; i += 8) {
        r0 = r0 + ld(i + 0); r1 = r1 + ld(i + 1);
        r2 = r2 + ld(i + 2); r3 = r3 + ld(i + 3);
        r4 = r4 + ld(i + 4); r5 = r5 + ld(i + 5);
        r6 = r6 + ld(i + 6); r7 = r7 + ld(i + 7);
    }
    return ((r0 + r1) + (r2 + r3)) + ((r4 + r5) + (r6 + r7));
}

// ---------------- K0: enorm[k] = np.sum(embed[k]*embed[k]) emulated ----------------
__global__ __launch_bounds__(256) void k0_norms(const float* __restrict__ embed,
                                                float* __restrict__ enorm) {
#pragma clang fp contract(off)
    int k = blockIdx.x * 256 + threadIdx.x;
    if (k >= K_) return;
    const float* e = embed + (size_t)k * D_;
    enorm[k] = np_sum128([&](int i) { float v = e[i]; return v * v; });
}

// ---------------- K1: zf[n][d] = einsum-f32 emulation (sequential c, mul+add, no FMA) ----------------
__global__ __launch_bounds__(256) void k1_proj(const float* __restrict__ z,
                                               const float* __restrict__ w,
                                               const float* __restrict__ bias,
                                               float* __restrict__ zp) {
#pragma clang fp contract(off)
    __shared__ float zs[64][64];    // [cc][hw_l]
    __shared__ float wsh[64][128];  // [cc][d]
    const int b   = blockIdx.x >> 4;
    const int hw0 = (blockIdx.x & 15) << 6;
    const int t   = threadIdx.x;
    const int hwg = (t & 7) * 8;
    const int dg  = (t >> 3) * 4;

    float acc[8][4];
#pragma unroll
    for (int i = 0; i < 8; ++i)
#pragma unroll
        for (int j = 0; j < 4; ++j) acc[i][j] = 0.f;

    for (int ct = 0; ct < C_; ct += 64) {
        __syncthreads();
#pragma unroll
        for (int i = 0; i < 16; ++i) {
            int idx = i * 256 + t;
            int cc = idx >> 6, hwl = idx & 63;
            zs[cc][hwl] = z[(((size_t)b * C_ + ct + cc) << 10) + hw0 + hwl];
        }
#pragma unroll
        for (int i = 0; i < 32; ++i) {
            int idx = i * 256 + t;
            int cc = idx >> 7, d = idx & 127;
            wsh[cc][d] = w[(size_t)d * C_ + ct + cc];
        }
        __syncthreads();
#pragma unroll 2
        for (int cc = 0; cc < 64; ++cc) {       // c strictly ascending across ct blocks
            float4 za = *(const float4*)&zs[cc][hwg];
            float4 zb = *(const float4*)&zs[cc][hwg + 4];
            float4 wv = *(const float4*)&wsh[cc][dg];
            float zv[8]  = {za.x, za.y, za.z, za.w, zb.x, zb.y, zb.z, zb.w};
            float wva[4] = {wv.x, wv.y, wv.z, wv.w};
#pragma unroll
            for (int i = 0; i < 8; ++i)
#pragma unroll
                for (int j = 0; j < 4; ++j) {
                    float p = zv[i] * wva[j];    // round mul
                    acc[i][j] = acc[i][j] + p;   // round add (no contraction)
                }
        }
    }
#pragma unroll
    for (int i = 0; i < 8; ++i)
#pragma unroll
        for (int j = 0; j < 4; ++j) {
            float v = acc[i][j] + bias[dg + j];
            zp[(((size_t)b * HW_ + hw0 + hwg + i) << 7) + dg + j] = v;
        }
}

// ---------------- K2: argmin_k of np-f32 B = fl32(fl32(Z - 2*zdot) + E) ----------------
// z-row lives ONLY in VGPRs: no LDS copy exists (prevents compiler LDS-remat,
// the R4/R5 bug). Refine is fully unrolled -> static zr indices, no scratch.
__global__ __launch_bounds__(256, 2) void k2_argmin(const float* __restrict__ zp,
                                                    const float* __restrict__ embed,
                                                    const float* __restrict__ enorm,
                                                    int* __restrict__ bestk_ws,
                                                    float* __restrict__ out_idx) {
#pragma clang fp contract(off)
    __shared__ float red_B[256];
    __shared__ int   red_k[256];
    const int t  = threadIdx.x;
    const int n0 = blockIdx.x * 64;
    const int rl = t & 63;

    // own row -> registers (coalesced within each wave's 64 lanes: consecutive rows)
    float zr[128];
    {
        const float4* zrow_g = (const float4*)(zp + ((size_t)(n0 + rl) << 7));
#pragma unroll
        for (int j = 0; j < 32; ++j) {
            float4 v = zrow_g[j];
            zr[j * 4 + 0] = v.x; zr[j * 4 + 1] = v.y;
            zr[j * 4 + 2] = v.z; zr[j * 4 + 3] = v.w;
        }
    }

    // znorm from registers: np.sum(zf*zf) — squares rounded, scalar-8 pairwise tree
    const float znorm = np_sum128([&](int i) { float v = zr[i]; return v * v; });

    const int kq   = __builtin_amdgcn_readfirstlane(t >> 6);  // wave-uniform k range
    const int kbeg = kq * 256;

    float best32 = 1e30f;          // f32 prefilter proxy: enorm - 2 z.e
    float bestB  = 1e30f;          // np-emulated quantized dist
    int   bestk  = K_;
    unsigned long long cand64 = 0; // 6 x 10-bit packed candidates (no scratch array)
    int   cnt = 0;

    auto refine = [&](int kk) {
#pragma clang fp contract(off)
        const float* e = embed + ((size_t)kk << 7);
        float s = 0.f;                        // sgemm: ascending-d f32 FMA chain
#pragma unroll                                 // full unroll: static zr refs, order kept (serial dep chain)
        for (int d2 = 0; d2 < 128; ++d2)
            s = fmaf(zr[d2], e[d2], s);
        float T  = 2.0f * s;
        float A  = znorm - T;                 // bin-maker 1 (mag ~13)
        float Bv = A + enorm[kk];             // bin-maker 2
        if (Bv < bestB || (Bv == bestB && kk < bestk)) { bestB = Bv; bestk = kk; }
    };
    auto flush = [&]() {
#pragma unroll
        for (int i = 0; i < 6; ++i)
            if (i < cnt) refine((int)((cand64 >> (10 * i)) & 1023ull));
        cand64 = 0; cnt = 0;
    };

#pragma unroll 1
    for (int k = kbeg; k < kbeg + 256; ++k) {
        const float4* e4 = (const float4*)(embed) + ((size_t)k << 5);  // wave-uniform
        float s0 = 0.f, s1 = 0.f, s2 = 0.f, s3 = 0.f;
#pragma unroll
        for (int j = 0; j < 32; j += 4) {
            float4 a  = e4[j + 0];
            float4 b2 = e4[j + 1];
            float4 c2 = e4[j + 2];
            float4 d2 = e4[j + 3];
            s0 = fmaf(zr[4*j +  0], a.x,  s0); s0 = fmaf(zr[4*j +  1], a.y,  s0);
            s0 = fmaf(zr[4*j +  2], a.z,  s0); s0 = fmaf(zr[4*j +  3], a.w,  s0);
            s1 = fmaf(zr[4*j +  4], b2.x, s1); s1 = fmaf(zr[4*j +  5], b2.y, s1);
            s1 = fmaf(zr[4*j +  6], b2.z, s1); s1 = fmaf(zr[4*j +  7], b2.w, s1);
            s2 = fmaf(zr[4*j +  8], c2.x, s2); s2 = fmaf(zr[4*j +  9], c2.y, s2);
            s2 = fmaf(zr[4*j + 10], c2.z, s2); s2 = fmaf(zr[4*j + 11], c2.w, s2);
            s3 = fmaf(zr[4*j + 12], d2.x, s3); s3 = fmaf(zr[4*j + 13], d2.y, s3);
            s3 = fmaf(zr[4*j + 14], d2.z, s3); s3 = fmaf(zr[4*j + 15], d2.w, s3);
        }
        float s    = (s0 + s1) + (s2 + s3);
        float dist = fmaf(-2.f, s, enorm[k]);
        if (dist < best32 + MARGIN) {        // np-winner provably buffered (bound ~6e-6)
            best32 = fminf(best32, dist);
            if (cnt == 6) flush();
            cand64 |= (unsigned long long)(k & 1023) << (10 * cnt);
            ++cnt;
        }
    }
    flush();

    red_B[t] = bestB; red_k[t] = bestk;
    __syncthreads();
    if (t < 64) {
        float bB = red_B[t]; int bk = red_k[t];
#pragma unroll
        for (int q = 1; q < 4; ++q) {
            float Bq = red_B[q * 64 + t]; int kq2 = red_k[q * 64 + t];
            if (Bq < bB || (Bq == bB && kq2 < bk)) { bB = Bq; bk = kq2; }
        }
        bestk_ws[n0 + t] = bk;
        out_idx[n0 + t]  = (float)bk;
    }
}

// ---------------- K3: gather + NCHW transpose ----------------
__global__ __launch_bounds__(256) void k3_gather(const float* __restrict__ embed,
                                                 const int* __restrict__ bestk,
                                                 float* __restrict__ out0) {
    __shared__ float tile[64][129];
    const int b   = blockIdx.x >> 4;
    const int hw0 = (blockIdx.x & 15) << 6;
    const int t   = threadIdx.x;
    const int n0  = b * HW_ + hw0;
#pragma unroll
    for (int i = 0; i < 32; ++i) {
        int idx = i * 256 + t;
        int hwl = idx >> 7, d = idx & 127;
        int k = bestk[n0 + hwl];
        tile[hwl][d] = embed[(size_t)k * 128 + d];
    }
    __syncthreads();
#pragma unroll
    for (int i = 0; i < 32; ++i) {
        int idx = i * 256 + t;
        int d = idx >> 6, hwl = idx & 63;
        out0[(((size_t)b * D_ + d) << 10) + hw0 + hwl] = tile[hwl][d];
    }
}

extern "C" void kernel_launch(void* const* d_in, const int* in_sizes, int n_in,
                              void* d_out, int out_size, void* d_ws, size_t ws_size,
                              hipStream_t stream) {
    const float* z     = (const float*)d_in[0];
    const float* pw    = (const float*)d_in[1];
    const float* pb    = (const float*)d_in[2];
    const float* embed = (const float*)d_in[3];

    float* out0 = (float*)d_out;
    float* out1 = (float*)d_out + (size_t)B_ * D_ * HW_;

    const size_t zp_bytes = (size_t)N_ * D_ * 4;           // 32 MB
    float* zp    = (float*)d_ws;
    float* enorm = (float*)((char*)d_ws + zp_bytes);
    int*   bestk = (int*)  ((char*)d_ws + zp_bytes + 4096);

    hipLaunchKernelGGL(k0_norms,  dim3(4),    dim3(256), 0, stream, embed, enorm);
    hipLaunchKernelGGL(k1_proj,   dim3(1024), dim3(256), 0, stream, z, pw, pb, zp);
    hipLaunchKernelGGL(k2_argmin, dim3(1024), dim3(256), 0, stream, zp, embed, enorm, bestk, out1);
    hipLaunchKernelGGL(k3_gather, dim3(1024), dim3(256), 0, stream, embed, bestk, out0);
}

// Round 7
// 1757.535 us; speedup vs baseline: 1.9676x; 1.0026x over previous
//
#include <hip/hip_runtime.h>

#define B_   64
#define C_   256
#define D_   128
#define HW_  1024
#define K_   1024
#define N_   65536
#define MARGIN 1e-5f

// numpy pairwise-sum emulation for n=128 contiguous f32 — SCALAR 8-accumulator
// path: r[j]=a[j]; for i=8..120 step 8: r[j]+=a[i+j];
// res = ((r0+r1)+(r2+r3)) + ((r4+r5)+(r6+r7)).   (verified: R4/R5/R6 passed)
template <typename F>
__device__ __forceinline__ float np_sum128(F ld) {
#pragma clang fp contract(off)
    float r0 = ld(0), r1 = ld(1), r2 = ld(2), r3 = ld(3);
    float r4 = ld(4), r5 = ld(5), r6 = ld(6), r7 = ld(7);
#pragma unroll
    for (int i = 8; i < 128; i += 8) {
        r0 = r0 + ld(i + 0); r1 = r1 + ld(i + 1);
        r2 = r2 + ld(i + 2); r3 = r3 + ld(i + 3);
        r4 = r4 + ld(i + 4); r5 = r5 + ld(i + 5);
        r6 = r6 + ld(i + 6); r7 = r7 + ld(i + 7);
    }
    return ((r0 + r1) + (r2 + r3)) + ((r4 + r5) + (r6 + r7));
}

// ---------------- K0: enorm[k] = np.sum(embed[k]*embed[k]) emulated ----------------
__global__ __launch_bounds__(256) void k0_norms(const float* __restrict__ embed,
                                                float* __restrict__ enorm) {
#pragma clang fp contract(off)
    int k = blockIdx.x * 256 + threadIdx.x;
    if (k >= K_) return;
    const float* e = embed + (size_t)k * D_;
    enorm[k] = np_sum128([&](int i) { float v = e[i]; return v * v; });
}

// ---------------- K1: zf[n][d] = einsum-f32 emulation (sequential c, mul+add, no FMA) ----------------
__global__ __launch_bounds__(256) void k1_proj(const float* __restrict__ z,
                                               const float* __restrict__ w,
                                               const float* __restrict__ bias,
                                               float* __restrict__ zp) {
#pragma clang fp contract(off)
    __shared__ float zs[64][64];    // [cc][hw_l]
    __shared__ float wsh[64][128];  // [cc][d]
    const int b   = blockIdx.x >> 4;
    const int hw0 = (blockIdx.x & 15) << 6;
    const int t   = threadIdx.x;
    const int hwg = (t & 7) * 8;
    const int dg  = (t >> 3) * 4;

    float acc[8][4];
#pragma unroll
    for (int i = 0; i < 8; ++i)
#pragma unroll
        for (int j = 0; j < 4; ++j) acc[i][j] = 0.f;

    for (int ct = 0; ct < C_; ct += 64) {
        __syncthreads();
#pragma unroll
        for (int i = 0; i < 16; ++i) {
            int idx = i * 256 + t;
            int cc = idx >> 6, hwl = idx & 63;
            zs[cc][hwl] = z[(((size_t)b * C_ + ct + cc) << 10) + hw0 + hwl];
        }
#pragma unroll
        for (int i = 0; i < 32; ++i) {
            int idx = i * 256 + t;
            int cc = idx >> 7, d = idx & 127;
            wsh[cc][d] = w[(size_t)d * C_ + ct + cc];
        }
        __syncthreads();
#pragma unroll 2
        for (int cc = 0; cc < 64; ++cc) {       // c strictly ascending across ct blocks
            float4 za = *(const float4*)&zs[cc][hwg];
            float4 zb = *(const float4*)&zs[cc][hwg + 4];
            float4 wv = *(const float4*)&wsh[cc][dg];
            float zv[8]  = {za.x, za.y, za.z, za.w, zb.x, zb.y, zb.z, zb.w};
            float wva[4] = {wv.x, wv.y, wv.z, wv.w};
#pragma unroll
            for (int i = 0; i < 8; ++i)
#pragma unroll
                for (int j = 0; j < 4; ++j) {
                    float p = zv[i] * wva[j];    // round mul
                    acc[i][j] = acc[i][j] + p;   // round add (no contraction)
                }
        }
    }
#pragma unroll
    for (int i = 0; i < 8; ++i)
#pragma unroll
        for (int j = 0; j < 4; ++j) {
            float v = acc[i][j] + bias[dg + j];
            zp[(((size_t)b * HW_ + hw0 + hwg + i) << 7) + dg + j] = v;
        }
}

// ---------------- K2: argmin_k of np-f32 B = fl32(fl32(Z - 2*zdot) + E) ----------------
// z-row lives ONLY in VGPRs. amdgpu_waves_per_eu(2,2) pins the allocator to
// exactly 2 waves/EU -> hard 256-VGPR budget, preventing the R6 spill-to-scratch
// (VGPR=128 + 27MB scratch WRITE_SIZE).
__global__ __launch_bounds__(256)
__attribute__((amdgpu_waves_per_eu(2, 2)))
void k2_argmin(const float* __restrict__ zp,
               const float* __restrict__ embed,
               const float* __restrict__ enorm,
               int* __restrict__ bestk_ws,
               float* __restrict__ out_idx) {
#pragma clang fp contract(off)
    __shared__ float red_B[256];
    __shared__ int   red_k[256];
    const int t  = threadIdx.x;
    const int n0 = blockIdx.x * 64;
    const int rl = t & 63;

    // own row -> registers (coalesced within each wave's 64 lanes: consecutive rows)
    float zr[128];
    {
        const float4* zrow_g = (const float4*)(zp + ((size_t)(n0 + rl) << 7));
#pragma unroll
        for (int j = 0; j < 32; ++j) {
            float4 v = zrow_g[j];
            zr[j * 4 + 0] = v.x; zr[j * 4 + 1] = v.y;
            zr[j * 4 + 2] = v.z; zr[j * 4 + 3] = v.w;
        }
    }

    // znorm from registers: np.sum(zf*zf) — squares rounded, scalar-8 pairwise tree
    const float znorm = np_sum128([&](int i) { float v = zr[i]; return v * v; });

    const int kq   = __builtin_amdgcn_readfirstlane(t >> 6);  // wave-uniform k range
    const int kbeg = kq * 256;

    float best32 = 1e30f;          // f32 prefilter proxy: enorm - 2 z.e
    float bestB  = 1e30f;          // np-emulated quantized dist
    int   bestk  = K_;
    unsigned long long cand64 = 0; // 6 x 10-bit packed candidates (no scratch array)
    int   cnt = 0;

    auto refine = [&](int kk) {
#pragma clang fp contract(off)
        const float* e = embed + ((size_t)kk << 7);
        float s = 0.f;                        // sgemm: ascending-d f32 FMA chain
#pragma unroll                                 // full unroll: static zr refs, serial dep chain kept
        for (int d2 = 0; d2 < 128; ++d2)
            s = fmaf(zr[d2], e[d2], s);
        float T  = 2.0f * s;
        float A  = znorm - T;                 // bin-maker 1 (mag ~13)
        float Bv = A + enorm[kk];             // bin-maker 2
        if (Bv < bestB || (Bv == bestB && kk < bestk)) { bestB = Bv; bestk = kk; }
    };
    auto flush = [&]() {
#pragma unroll
        for (int i = 0; i < 6; ++i)
            if (i < cnt) refine((int)((cand64 >> (10 * i)) & 1023ull));
        cand64 = 0; cnt = 0;
    };

#pragma unroll 1
    for (int k = kbeg; k < kbeg + 256; ++k) {
        const float4* e4 = (const float4*)(embed) + ((size_t)k << 5);  // wave-uniform
        float s0 = 0.f, s1 = 0.f, s2 = 0.f, s3 = 0.f;
#pragma unroll
        for (int j = 0; j < 32; j += 4) {
            float4 a  = e4[j + 0];
            float4 b2 = e4[j + 1];
            float4 c2 = e4[j + 2];
            float4 d2 = e4[j + 3];
            s0 = fmaf(zr[4*j +  0], a.x,  s0); s0 = fmaf(zr[4*j +  1], a.y,  s0);
            s0 = fmaf(zr[4*j +  2], a.z,  s0); s0 = fmaf(zr[4*j +  3], a.w,  s0);
            s1 = fmaf(zr[4*j +  4], b2.x, s1); s1 = fmaf(zr[4*j +  5], b2.y, s1);
            s1 = fmaf(zr[4*j +  6], b2.z, s1); s1 = fmaf(zr[4*j +  7], b2.w, s1);
            s2 = fmaf(zr[4*j +  8], c2.x, s2); s2 = fmaf(zr[4*j +  9], c2.y, s2);
            s2 = fmaf(zr[4*j + 10], c2.z, s2); s2 = fmaf(zr[4*j + 11], c2.w, s2);
            s3 = fmaf(zr[4*j + 12], d2.x, s3); s3 = fmaf(zr[4*j + 13], d2.y, s3);
            s3 = fmaf(zr[4*j + 14], d2.z, s3); s3 = fmaf(zr[4*j + 15], d2.w, s3);
        }
        float s    = (s0 + s1) + (s2 + s3);
        float dist = fmaf(-2.f, s, enorm[k]);
        if (dist < best32 + MARGIN) {        // np-winner provably buffered (bound ~6e-6)
            best32 = fminf(best32, dist);
            if (cnt == 6) flush();
            cand64 |= (unsigned long long)(k & 1023) << (10 * cnt);
            ++cnt;
        }
    }
    flush();

    red_B[t] = bestB; red_k[t] = bestk;
    __syncthreads();
    if (t < 64) {
        float bB = red_B[t]; int bk = red_k[t];
#pragma unroll
        for (int q = 1; q < 4; ++q) {
            float Bq = red_B[q * 64 + t]; int kq2 = red_k[q * 64 + t];
            if (Bq < bB || (Bq == bB && kq2 < bk)) { bB = Bq; bk = kq2; }
        }
        bestk_ws[n0 + t] = bk;
        out_idx[n0 + t]  = (float)bk;
    }
}

// ---------------- K3: gather + NCHW transpose ----------------
__global__ __launch_bounds__(256) void k3_gather(const float* __restrict__ embed,
                                                 const int* __restrict__ bestk,
                                                 float* __restrict__ out0) {
    __shared__ float tile[64][129];
    const int b   = blockIdx.x >> 4;
    const int hw0 = (blockIdx.x & 15) << 6;
    const int t   = threadIdx.x;
    const int n0  = b * HW_ + hw0;
#pragma unroll
    for (int i = 0; i < 32; ++i) {
        int idx = i * 256 + t;
        int hwl = idx >> 7, d = idx & 127;
        int k = bestk[n0 + hwl];
        tile[hwl][d] = embed[(size_t)k * 128 + d];
    }
    __syncthreads();
#pragma unroll
    for (int i = 0; i < 32; ++i) {
        int idx = i * 256 + t;
        int d = idx >> 6, hwl = idx & 63;
        out0[(((size_t)b * D_ + d) << 10) + hw0 + hwl] = tile[hwl][d];
    }
}

extern "C" void kernel_launch(void* const* d_in, const int* in_sizes, int n_in,
                              void* d_out, int out_size, void* d_ws, size_t ws_size,
                              hipStream_t stream) {
    const float* z     = (const float*)d_in[0];
    const float* pw    = (const float*)d_in[1];
    const float* pb    = (const float*)d_in[2];
    const float* embed = (const float*)d_in[3];

    float* out0 = (float*)d_out;
    float* out1 = (float*)d_out + (size_t)B_ * D_ * HW_;

    const size_t zp_bytes = (size_t)N_ * D_ * 4;           // 32 MB
    float* zp    = (float*)d_ws;
    float* enorm = (float*)((char*)d_ws + zp_bytes);
    int*   bestk = (int*)  ((char*)d_ws + zp_bytes + 4096);

    hipLaunchKernelGGL(k0_norms,  dim3(4),    dim3(256), 0, stream, embed, enorm);
    hipLaunchKernelGGL(k1_proj,   dim3(1024), dim3(256), 0, stream, z, pw, pb, zp);
    hipLaunchKernelGGL(k2_argmin, dim3(1024), dim3(256), 0, stream, zp, embed, enorm, bestk, out1);
    hipLaunchKernelGGL(k3_gather, dim3(1024), dim3(256), 0, stream, embed, bestk, out0);
}